// Round 14
// baseline (548.380 us; speedup 1.0000x reference)
//
#include <hip/hip_runtime.h>

#define W 64
#define D 256
#define NH 8

typedef unsigned short u16;
typedef unsigned int u32;
typedef __attribute__((ext_vector_type(8))) short bf16x8;
typedef __attribute__((ext_vector_type(4))) float f32x4;

__device__ __forceinline__ u16 f2bf(float f) {
    union { float f; unsigned u; } v; v.f = f;
    unsigned r = v.u + 0x7fffu + ((v.u >> 16) & 1u);
    return (u16)(r >> 16);
}
__device__ __forceinline__ u32 pk2(float lo, float hi) {
    return (u32)f2bf(lo) | ((u32)f2bf(hi) << 16);
}
typedef union { u32 w[4]; bf16x8 f; } frag_u;
// fragment element j <- (a,b)[j>>2][j&3]  (tau-order packing)
__device__ __forceinline__ bf16x8 pack8(f32x4 a, f32x4 b) {
    frag_u u;
    u.w[0] = pk2(a[0], a[1]);
    u.w[1] = pk2(a[2], a[3]);
    u.w[2] = pk2(b[0], b[1]);
    u.w[3] = pk2(b[2], b[3]);
    return u.f;
}

// ---------------- LDS layout (bytes) ----------------
// xs   : [64][264] u16  x bf16 staging; dead after QKV; aliased by attn_out 33792
// buf  : per-wave [16][72] u16 (V transpose 2-pass, then P per q-tile)       2304 x 8
// bias : [8][128] f32 rel-pos bias table                                     4096
// total 56320 -> 2 blocks/CU (register-capped at 4 waves/SIMD regardless)
// Q,K never touch LDS: swapped-operand GEMM gives fragments in tau-channel
// order c(g,j)=16(j>>2)+4g+(j&3); S^T=mfma(kf,qf) contracts consistently
// (verified correct in R12's passing run). V/P keep the R10 buf paths with
// full lgkmcnt(0) drains -- the proven no-spill schedule anchor.
#define XS_ROW 264
#define BUF_ROW 72
#define OFF_BUF 33792
#define OFF_BIAS 52224

__global__ __launch_bounds__(512, 4) void win_attn11(
    const float* __restrict__ x, const float* __restrict__ bqkv,
    const float* __restrict__ bproj, const float* __restrict__ relb,
    const u16* __restrict__ wqkvT, const u16* __restrict__ wprojT,
    float* __restrict__ out)
{
    __shared__ __align__(16) char smem[56320];

    const int tid  = threadIdx.x;
    const int lane = tid & 63;
    const int h    = tid >> 6;      // wave index == head
    const int l15  = lane & 15;
    const int g    = lane >> 4;
    const int w    = blockIdx.x;

    u16*   xs      = (u16*)smem;
    u16*   buf     = (u16*)(smem + OFF_BUF) + h * 16 * BUF_ROW;
    float* bias_ld = (float*)(smem + OFF_BIAS);

    const f32x4 z4 = {0.f, 0.f, 0.f, 0.f};

    // ---------- Phase 0: bias table + stage x window -> LDS bf16 ----------
    for (int i = tid; i < NH * 127; i += 512)
        bias_ld[(i / 127) * 128 + (i % 127)] = relb[i];

    const float* xw = x + (size_t)w * (W * D);
    #pragma unroll
    for (int i = 0; i < 8; ++i) {
        int e = i * 2048 + tid * 4;
        int row = e >> 8, col = e & 255;
        float4 v = *(const float4*)(xw + e);
        ushort4 b;
        b.x = f2bf(v.x); b.y = f2bf(v.y); b.z = f2bf(v.z); b.w = f2bf(v.w);
        *(ushort4*)(xs + row * XS_ROW + col) = b;
    }
    __syncthreads();

    // ---------- Phase 1a: Q,K via swapped GEMM (M=channels, N=tokens) ----------
    // Output: lane l15 = token (within q-tile nt), regs (mt,r) = channel
    // 16mt+4g+r -> pack8 puts channels in tau order on both qf and kf.
    bf16x8 qf[4], kf[4], vf[2][2];

    #pragma unroll
    for (int mat = 0; mat < 2; ++mat) {
        f32x4 acc[2][4];
        #pragma unroll
        for (int mt = 0; mt < 2; ++mt)
            #pragma unroll
            for (int nt = 0; nt < 4; ++nt)
                acc[mt][nt] = z4;

        const u16* w0 = wqkvT + (size_t)(mat * 256 + h * 32 + l15) * 256;
        const u16* w1 = w0 + 16 * 256;
        #pragma unroll
        for (int ks = 0; ks < 8; ++ks) {
            bf16x8 a0 = *(const bf16x8*)(w0 + ks * 32 + g * 8);
            bf16x8 a1 = *(const bf16x8*)(w1 + ks * 32 + g * 8);
            #pragma unroll
            for (int nt = 0; nt < 4; ++nt) {
                bf16x8 xb = *(const bf16x8*)(xs + (16 * nt + l15) * XS_ROW + ks * 32 + g * 8);
                acc[0][nt] = __builtin_amdgcn_mfma_f32_16x16x32_bf16(a0, xb, acc[0][nt], 0, 0, 0);
                acc[1][nt] = __builtin_amdgcn_mfma_f32_16x16x32_bf16(a1, xb, acc[1][nt], 0, 0, 0);
            }
        }
        const float* bb = bqkv + mat * 256 + h * 32 + 4 * g;
        f32x4 b0v, b1v;
        #pragma unroll
        for (int r = 0; r < 4; ++r) { b0v[r] = bb[r]; b1v[r] = bb[16 + r]; }
        #pragma unroll
        for (int nt = 0; nt < 4; ++nt) {
            bf16x8 fr = pack8(acc[0][nt] + b0v, acc[1][nt] + b1v);
            if (mat == 0) qf[nt] = fr; else kf[nt] = fr;
        }
    }

    // ---------- Phase 1b: V via normal GEMM + buf transpose (R10 path) ----------
    {
        f32x4 acc[2][4];
        #pragma unroll
        for (int ct = 0; ct < 2; ++ct)
            #pragma unroll
            for (int rt = 0; rt < 4; ++rt)
                acc[ct][rt] = z4;

        const u16* bp0 = wqkvT + (size_t)(512 + h * 32 + l15) * 256;
        const u16* bp1 = bp0 + 16 * 256;
        #pragma unroll
        for (int ks = 0; ks < 8; ++ks) {
            bf16x8 b0 = *(const bf16x8*)(bp0 + ks * 32 + g * 8);
            bf16x8 b1 = *(const bf16x8*)(bp1 + ks * 32 + g * 8);
            #pragma unroll
            for (int rt = 0; rt < 4; ++rt) {
                bf16x8 a = *(const bf16x8*)(xs + (16 * rt + l15) * XS_ROW + ks * 32 + g * 8);
                acc[0][rt] = __builtin_amdgcn_mfma_f32_16x16x32_bf16(a, b0, acc[0][rt], 0, 0, 0);
                acc[1][rt] = __builtin_amdgcn_mfma_f32_16x16x32_bf16(a, b1, acc[1][rt], 0, 0, 0);
            }
        }
        const float bias0 = bqkv[512 + h * 32 + l15];
        const float bias1 = bqkv[512 + h * 32 + 16 + l15];

        asm volatile("s_waitcnt lgkmcnt(0)" ::: "memory");
        #pragma unroll
        for (int cd = 0; cd < 2; ++cd) {
            const float bias = cd ? bias1 : bias0;
            #pragma unroll
            for (int rt = 0; rt < 4; ++rt) {
                ushort4 pk;
                pk.x = f2bf(acc[cd][rt][0] + bias);
                pk.y = f2bf(acc[cd][rt][1] + bias);
                pk.z = f2bf(acc[cd][rt][2] + bias);
                pk.w = f2bf(acc[cd][rt][3] + bias);
                *(ushort4*)(buf + l15 * BUF_ROW + 16 * rt + 4 * g) = pk;
            }
            asm volatile("s_waitcnt lgkmcnt(0)" ::: "memory");
            #pragma unroll
            for (int ks = 0; ks < 2; ++ks)
                vf[ks][cd] = *(const bf16x8*)(buf + l15 * BUF_ROW + ks * 32 + g * 8);
            asm volatile("s_waitcnt lgkmcnt(0)" ::: "memory");
        }
    }
    __syncthreads();   // all xs reads done -> ao may alias xs

    // ---------- Phase 2: attention. S^T = mfma(kf, qf): lane = q, regs = k ----------
    const float scale = 0.17677669529663687f;   // 1/sqrt(32)
    u16* ao = xs;
    // bias index: 63 + k - q, k = 16mtk+4g+r, q = 16nt+l15
    const float* blb = bias_ld + h * 128 + 63 + 4 * g - l15;

    #pragma unroll
    for (int nt = 0; nt < 4; ++nt) {
        f32x4 st[4];
        #pragma unroll
        for (int mtk = 0; mtk < 4; ++mtk)
            st[mtk] = __builtin_amdgcn_mfma_f32_16x16x32_bf16(kf[mtk], qf[nt], z4, 0, 0, 0);

        asm volatile("s_waitcnt lgkmcnt(0)" ::: "memory");   // WAR: prior buf reads done
        const float* bl = blb - 16 * nt;
        float esum = 0.f;
        #pragma unroll
        for (int mtk = 0; mtk < 4; ++mtk) {
            ushort4 pk;
            #pragma unroll
            for (int r = 0; r < 4; ++r) {
                float sv = st[mtk][r] * scale + bl[16 * mtk + r];
                float e = __expf(sv);
                esum += e;
                ((u16*)&pk)[r] = f2bf(e);
            }
            // P[q][k]: row = q_local l15, cols k = 16mtk+4g..+3 (unnormalized)
            *(ushort4*)(buf + l15 * BUF_ROW + 16 * mtk + 4 * g) = pk;
        }
        esum += __shfl_xor(esum, 16, 64);
        esum += __shfl_xor(esum, 32, 64);
        const float inv = 1.0f / esum;

        asm volatile("s_waitcnt lgkmcnt(0)" ::: "memory");
        bf16x8 pf0 = *(const bf16x8*)(buf + l15 * BUF_ROW + g * 8);
        bf16x8 pf1 = *(const bf16x8*)(buf + l15 * BUF_ROW + 32 + g * 8);
        #pragma unroll
        for (int cd = 0; cd < 2; ++cd) {
            // O^T: A = vf (lane = d-channel, elems = tokens), B = pf (lane = q)
            f32x4 o = __builtin_amdgcn_mfma_f32_16x16x32_bf16(vf[0][cd], pf0, z4, 0, 0, 0);
            o = __builtin_amdgcn_mfma_f32_16x16x32_bf16(vf[1][cd], pf1, o, 0, 0, 0);
            // output: lane = q-token, regs r = d = 16cd+4g+r
            uint2 pkd;
            pkd.x = pk2(o[0] * inv, o[1] * inv);
            pkd.y = pk2(o[2] * inv, o[3] * inv);
            *(uint2*)(ao + (16 * nt + l15) * XS_ROW + h * 32 + 16 * cd + 4 * g) = pkd;
        }
        asm volatile("s_waitcnt lgkmcnt(0)" ::: "memory");   // WAR before next nt
    }
    __syncthreads();   // ao complete (cross-wave input to proj)

    // ---------- Phase 3: output projection (wave h -> cols h*32..+31) ----------
    f32x4 pacc[2][4];
    #pragma unroll
    for (int ct = 0; ct < 2; ++ct)
        #pragma unroll
        for (int rt = 0; rt < 4; ++rt)
            pacc[ct][rt] = z4;

    const u16* pp0 = wprojT + (size_t)(h * 32 + l15) * 256;
    const u16* pp1 = pp0 + 16 * 256;
    #pragma unroll
    for (int ks = 0; ks < 8; ++ks) {
        bf16x8 b0 = *(const bf16x8*)(pp0 + ks * 32 + g * 8);
        bf16x8 b1 = *(const bf16x8*)(pp1 + ks * 32 + g * 8);
        #pragma unroll
        for (int rt = 0; rt < 4; ++rt) {
            bf16x8 a = *(const bf16x8*)(ao + (16 * rt + l15) * XS_ROW + ks * 32 + g * 8);
            pacc[0][rt] = __builtin_amdgcn_mfma_f32_16x16x32_bf16(a, b0, pacc[0][rt], 0, 0, 0);
            pacc[1][rt] = __builtin_amdgcn_mfma_f32_16x16x32_bf16(a, b1, pacc[1][rt], 0, 0, 0);
        }
    }
    float* outw = out + (size_t)w * (W * D);
    #pragma unroll
    for (int ct = 0; ct < 2; ++ct) {
        const int n = h * 32 + ct * 16 + l15;
        const float bp = bproj[n];
        #pragma unroll
        for (int rt = 0; rt < 4; ++rt)
            #pragma unroll
            for (int r = 0; r < 4; ++r)
                outw[(16 * rt + 4 * g + r) * D + n] = pacc[ct][rt][r] + bp;
    }
}

// Transpose + bf16-convert the weight matrices into workspace (L2-resident).
__global__ void prep_weights(const float* __restrict__ wqkv, const float* __restrict__ wproj,
                             u16* __restrict__ wqkvT, u16* __restrict__ wprojT)
{
    int i = blockIdx.x * 256 + threadIdx.x;
    if (i < 768 * 256) {
        int n = i >> 8, kk = i & 255;
        wqkvT[i] = f2bf(wqkv[kk * 768 + n]);
    } else {
        int j = i - 768 * 256;
        int n = j >> 8, kk = j & 255;
        wprojT[j] = f2bf(wproj[kk * 256 + n]);
    }
}

extern "C" void kernel_launch(void* const* d_in, const int* in_sizes, int n_in,
                              void* d_out, int out_size, void* d_ws, size_t ws_size,
                              hipStream_t stream)
{
    const float* x     = (const float*)d_in[0];
    const float* wqkv  = (const float*)d_in[1];
    const float* bqkv  = (const float*)d_in[2];
    const float* wproj = (const float*)d_in[3];
    const float* bproj = (const float*)d_in[4];
    const float* relb  = (const float*)d_in[5];

    u16* wqkvT  = (u16*)d_ws;                 // 768*256 u16
    u16* wprojT = wqkvT + 768 * 256;          // 256*256 u16

    prep_weights<<<1024, 256, 0, stream>>>(wqkv, wproj, wqkvT, wprojT);

    const int nwin = in_sizes[0] / (W * D);   // 4096
    win_attn11<<<nwin, 512, 0, stream>>>(x, bqkv, bproj, relb, wqkvT, wprojT, (float*)d_out);
}

// Round 15
// 506.701 us; speedup vs baseline: 1.0823x; 1.0823x over previous
//
#include <hip/hip_runtime.h>

#define W 64
#define D 256
#define NH 8

typedef unsigned short u16;
typedef __attribute__((ext_vector_type(8))) short bf16x8;
typedef __attribute__((ext_vector_type(4))) float f32x4;

__device__ __forceinline__ u16 f2bf(float f) {
    union { float f; unsigned u; } v; v.f = f;
    unsigned r = v.u + 0x7fffu + ((v.u >> 16) & 1u);
    return (u16)(r >> 16);
}

// =============== K1: QKV + attention (R10 per-wave code), ao -> global bf16 ===============
// LDS: xs [64][264] u16 (33792) + per-wave buf [16][72] u16 (2304 x 8) = 52224.
// ONE barrier (post-staging); afterwards 16 waves/CU free-run (no lockstep).
// All wave-private lgkmcnt(0) drains kept verbatim: they are the proven
// no-spill regalloc anchor (R9/R13 showed removing/replacing them spills).
#define XS_ROW 264
#define BUF_ROW 72
#define OFF_BUF 33792

__global__ __launch_bounds__(512, 4) void qkv_attn(
    const float* __restrict__ x, const float* __restrict__ bqkv,
    const float* __restrict__ relb, const u16* __restrict__ wqkvT,
    u16* __restrict__ aog)
{
    __shared__ __align__(16) char smem[52224];

    const int tid  = threadIdx.x;
    const int lane = tid & 63;
    const int h    = tid >> 6;      // wave index == head
    const int l15  = lane & 15;
    const int g    = lane >> 4;
    const int w    = blockIdx.x;

    u16* xs  = (u16*)smem;
    u16* buf = (u16*)(smem + OFF_BUF) + h * 16 * BUF_ROW;

    const f32x4 z4 = {0.f, 0.f, 0.f, 0.f};

    // ---------- Phase 0: stage x window -> LDS bf16 ----------
    const float* xw = x + (size_t)w * (W * D);
    #pragma unroll
    for (int i = 0; i < 8; ++i) {
        int e = i * 2048 + tid * 4;
        int row = e >> 8, col = e & 255;
        float4 v = *(const float4*)(xw + e);
        ushort4 b;
        b.x = f2bf(v.x); b.y = f2bf(v.y); b.z = f2bf(v.z); b.w = f2bf(v.w);
        *(ushort4*)(xs + row * XS_ROW + col) = b;
    }
    __syncthreads();   // the ONLY barrier: xs read-only afterwards

    // ---------- Phase 1: QKV for head h; fragments kept in registers ----------
    bf16x8 qf[4], kf[4], vf[2][2];

    #pragma unroll
    for (int mat = 0; mat < 3; ++mat) {
        f32x4 acc[2][4];
        #pragma unroll
        for (int ct = 0; ct < 2; ++ct)
            #pragma unroll
            for (int rt = 0; rt < 4; ++rt)
                acc[ct][rt] = z4;

        const u16* bp0 = wqkvT + (size_t)(mat * 256 + h * 32 + l15) * 256;
        const u16* bp1 = bp0 + 16 * 256;
        #pragma unroll
        for (int ks = 0; ks < 8; ++ks) {
            bf16x8 b0 = *(const bf16x8*)(bp0 + ks * 32 + g * 8);
            bf16x8 b1 = *(const bf16x8*)(bp1 + ks * 32 + g * 8);
            #pragma unroll
            for (int rt = 0; rt < 4; ++rt) {
                bf16x8 a = *(const bf16x8*)(xs + (16 * rt + l15) * XS_ROW + ks * 32 + g * 8);
                acc[0][rt] = __builtin_amdgcn_mfma_f32_16x16x32_bf16(a, b0, acc[0][rt], 0, 0, 0);
                acc[1][rt] = __builtin_amdgcn_mfma_f32_16x16x32_bf16(a, b1, acc[1][rt], 0, 0, 0);
            }
        }
        const float bias0 = bqkv[mat * 256 + h * 32 + l15];
        const float bias1 = bqkv[mat * 256 + h * 32 + 16 + l15];

        asm volatile("s_waitcnt lgkmcnt(0)" ::: "memory");   // WAR: prior buf reads done
        if (mat < 2) {
            // C-layout (lane=d col, row=4g+r) -> A-frag layout, 2 row-tiles per pass
            #pragma unroll
            for (int rp = 0; rp < 2; ++rp) {
                #pragma unroll
                for (int ct = 0; ct < 2; ++ct) {
                    const float bias = ct ? bias1 : bias0;
                    #pragma unroll
                    for (int rtl = 0; rtl < 2; ++rtl)
                        #pragma unroll
                        for (int r = 0; r < 4; ++r)
                            buf[(4 * g + r) * BUF_ROW + rtl * 32 + ct * 16 + l15] =
                                f2bf(acc[ct][2 * rp + rtl][r] + bias);
                }
                asm volatile("s_waitcnt lgkmcnt(0)" ::: "memory");
                #pragma unroll
                for (int rtl = 0; rtl < 2; ++rtl) {
                    bf16x8 fr = *(const bf16x8*)(buf + l15 * BUF_ROW + rtl * 32 + g * 8);
                    if (mat == 0) qf[2 * rp + rtl] = fr; else kf[2 * rp + rtl] = fr;
                }
                asm volatile("s_waitcnt lgkmcnt(0)" ::: "memory");   // WAR before next pass
            }
        } else {
            // v transposed: one cd (16 d-cols) per pass; token index packed b64
            #pragma unroll
            for (int cd = 0; cd < 2; ++cd) {
                const float bias = cd ? bias1 : bias0;
                #pragma unroll
                for (int rt = 0; rt < 4; ++rt) {
                    ushort4 pk;
                    pk.x = f2bf(acc[cd][rt][0] + bias);
                    pk.y = f2bf(acc[cd][rt][1] + bias);
                    pk.z = f2bf(acc[cd][rt][2] + bias);
                    pk.w = f2bf(acc[cd][rt][3] + bias);
                    *(ushort4*)(buf + l15 * BUF_ROW + 16 * rt + 4 * g) = pk;
                }
                asm volatile("s_waitcnt lgkmcnt(0)" ::: "memory");
                #pragma unroll
                for (int ks = 0; ks < 2; ++ks)
                    vf[ks][cd] = *(const bf16x8*)(buf + l15 * BUF_ROW + ks * 32 + g * 8);
                asm volatile("s_waitcnt lgkmcnt(0)" ::: "memory");   // WAR before next pass
            }
        }
    }

    // ---------- Phase 2: attention (wave-private); ao -> GLOBAL bf16 ----------
    const float* b2 = relb + h * 127;
    const float scale = 0.17677669529663687f;   // 1/sqrt(32)
    u16* aw = aog + (size_t)w * (W * D) + h * 32;

    #pragma unroll
    for (int rt = 0; rt < 4; ++rt) {
        f32x4 s[4];
        #pragma unroll
        for (int ct = 0; ct < 4; ++ct)
            s[ct] = __builtin_amdgcn_mfma_f32_16x16x32_bf16(qf[rt], kf[ct], z4, 0, 0, 0);

        asm volatile("s_waitcnt lgkmcnt(0)" ::: "memory");   // WAR: prev rt's pf reads done
        float psum[4] = {0.f, 0.f, 0.f, 0.f};
        #pragma unroll
        for (int ct = 0; ct < 4; ++ct) {
            const int ktok = 16 * ct + l15;
            #pragma unroll
            for (int r = 0; r < 4; ++r) {
                const int qtok = 16 * rt + 4 * g + r;
                float sv = s[ct][r] * scale + b2[ktok - qtok + 63];
                float ee = __expf(sv);
                psum[r] += ee;
                buf[(4 * g + r) * BUF_ROW + ct * 16 + l15] = f2bf(ee);
            }
        }
        float inv[4];
        #pragma unroll
        for (int r = 0; r < 4; ++r) {
            float sum = psum[r];
            #pragma unroll
            for (int m = 1; m <= 8; m <<= 1)
                sum += __shfl_xor(sum, m, 64);
            inv[r] = 1.0f / sum;
        }
        asm volatile("s_waitcnt lgkmcnt(0)" ::: "memory");
        bf16x8 pf0 = *(const bf16x8*)(buf + l15 * BUF_ROW + g * 8);
        bf16x8 pf1 = *(const bf16x8*)(buf + l15 * BUF_ROW + 32 + g * 8);
        #pragma unroll
        for (int cd = 0; cd < 2; ++cd) {
            f32x4 o = __builtin_amdgcn_mfma_f32_16x16x32_bf16(pf0, vf[0][cd], z4, 0, 0, 0);
            o = __builtin_amdgcn_mfma_f32_16x16x32_bf16(pf1, vf[1][cd], o, 0, 0, 0);
            #pragma unroll
            for (int r = 0; r < 4; ++r)
                aw[(size_t)(16 * rt + 4 * g + r) * D + cd * 16 + l15] = f2bf(o[r] * inv[r]);
        }
        asm volatile("s_waitcnt lgkmcnt(0)" ::: "memory");   // WAR before next rt
    }
}

// =============== K2: output projection, 1-wave blocks, zero LDS/barriers ===============
__global__ __launch_bounds__(64, 4) void proj_out(
    const u16* __restrict__ aog, const float* __restrict__ bproj,
    const u16* __restrict__ wprojT, float* __restrict__ out)
{
    const int w = blockIdx.x >> 3;
    const int h = blockIdx.x & 7;
    const int lane = threadIdx.x;
    const int l15 = lane & 15;
    const int g   = lane >> 4;

    const f32x4 z4 = {0.f, 0.f, 0.f, 0.f};
    const u16* ar = aog + (size_t)w * (W * D);

    f32x4 pacc[2][4];
    #pragma unroll
    for (int ct = 0; ct < 2; ++ct)
        #pragma unroll
        for (int rt = 0; rt < 4; ++rt)
            pacc[ct][rt] = z4;

    const u16* pp0 = wprojT + (size_t)(h * 32 + l15) * 256;
    const u16* pp1 = pp0 + 16 * 256;
    #pragma unroll
    for (int ks = 0; ks < 8; ++ks) {
        bf16x8 b0 = *(const bf16x8*)(pp0 + ks * 32 + g * 8);
        bf16x8 b1 = *(const bf16x8*)(pp1 + ks * 32 + g * 8);
        #pragma unroll
        for (int rt = 0; rt < 4; ++rt) {
            bf16x8 a = *(const bf16x8*)(ar + (size_t)(16 * rt + l15) * D + ks * 32 + g * 8);
            pacc[0][rt] = __builtin_amdgcn_mfma_f32_16x16x32_bf16(a, b0, pacc[0][rt], 0, 0, 0);
            pacc[1][rt] = __builtin_amdgcn_mfma_f32_16x16x32_bf16(a, b1, pacc[1][rt], 0, 0, 0);
        }
    }
    float* outw = out + (size_t)w * (W * D);
    #pragma unroll
    for (int ct = 0; ct < 2; ++ct) {
        const int n = h * 32 + ct * 16 + l15;
        const float bp = bproj[n];
        #pragma unroll
        for (int rt = 0; rt < 4; ++rt)
            #pragma unroll
            for (int r = 0; r < 4; ++r)
                outw[(size_t)(16 * rt + 4 * g + r) * D + n] = pacc[ct][rt][r] + bp;
    }
}

// Transpose + bf16-convert the weight matrices into workspace (L2-resident).
__global__ void prep_weights(const float* __restrict__ wqkv, const float* __restrict__ wproj,
                             u16* __restrict__ wqkvT, u16* __restrict__ wprojT)
{
    int i = blockIdx.x * 256 + threadIdx.x;
    if (i < 768 * 256) {
        int n = i >> 8, kk = i & 255;
        wqkvT[i] = f2bf(wqkv[kk * 768 + n]);
    } else {
        int j = i - 768 * 256;
        int n = j >> 8, kk = j & 255;
        wprojT[j] = f2bf(wproj[kk * 256 + n]);
    }
}

extern "C" void kernel_launch(void* const* d_in, const int* in_sizes, int n_in,
                              void* d_out, int out_size, void* d_ws, size_t ws_size,
                              hipStream_t stream)
{
    const float* x     = (const float*)d_in[0];
    const float* wqkv  = (const float*)d_in[1];
    const float* bqkv  = (const float*)d_in[2];
    const float* wproj = (const float*)d_in[3];
    const float* bproj = (const float*)d_in[4];
    const float* relb  = (const float*)d_in[5];

    u16* wqkvT  = (u16*)d_ws;                 // 768*256 u16 = 393216 B
    u16* wprojT = wqkvT + 768 * 256;          // 256*256 u16 -> ends 524288 B
    u16* aog    = (u16*)((char*)d_ws + 524288);   // [4096][64][256] bf16 = 134 MB
                                                  // (ws >= 403 MB proven in R4)

    prep_weights<<<1024, 256, 0, stream>>>(wqkv, wproj, wqkvT, wprojT);

    const int nwin = in_sizes[0] / (W * D);   // 4096
    qkv_attn<<<nwin, 512, 0, stream>>>(x, bqkv, relb, wqkvT, aog);
    proj_out<<<nwin * NH, 64, 0, stream>>>(aog, bproj, wprojT, (float*)d_out);
}

// Round 16
// 368.221 us; speedup vs baseline: 1.4893x; 1.3761x over previous
//
#include <hip/hip_runtime.h>
#include <hip/hip_bf16.h>

#define W 64
#define D 256
#define NH 8

typedef unsigned short u16;
typedef __attribute__((ext_vector_type(8))) short bf16x8;
typedef __attribute__((ext_vector_type(4))) float f32x4;

// Native RNE f32->bf16: compiler emits v_cvt_pk_bf16_f32 for pairs (1 inst / 2 vals).
__device__ __forceinline__ u16 bfc(float f) {
    __hip_bfloat16 h = __float2bfloat16(f);
    return *reinterpret_cast<u16*>(&h);
}

// ---------------- LDS layout (bytes) ----------------
// xs  : [64][264] u16   x bf16 staging; dead after QKV; aliased by attn_out  33792
// buf : per-wave [16][72] u16 transposer (q/k 2-pass, v 2-pass, P)            2304 x 8
// total 52224. Occupancy is register-capped at 2 blocks/CU (R10 analysis);
// the full lgkmcnt(0) drains are the proven no-spill regalloc anchor
// (R9/R13/R14: any removal/replacement spills).
#define XS_ROW 264
#define BUF_ROW 72
#define OFF_BUF 33792

__global__ __launch_bounds__(512, 4) void win_attn12(
    const float* __restrict__ x, const float* __restrict__ bqkv,
    const float* __restrict__ bproj, const float* __restrict__ relb,
    const u16* __restrict__ wqkvT, const u16* __restrict__ wprojT,
    float* __restrict__ out)
{
    __shared__ __align__(16) char smem[52224];

    const int tid  = threadIdx.x;
    const int lane = tid & 63;
    const int h    = tid >> 6;      // wave index == head
    const int l15  = lane & 15;
    const int g    = lane >> 4;
    const int w    = blockIdx.x;

    u16* xs  = (u16*)smem;
    u16* buf = (u16*)(smem + OFF_BUF) + h * 16 * BUF_ROW;

    const f32x4 z4 = {0.f, 0.f, 0.f, 0.f};

    // ---------- Phase 0: stage x window -> LDS bf16 ----------
    const float* xw = x + (size_t)w * (W * D);
    #pragma unroll
    for (int i = 0; i < 8; ++i) {
        int e = i * 2048 + tid * 4;
        int row = e >> 8, col = e & 255;
        float4 v = *(const float4*)(xw + e);
        ushort4 b;
        b.x = bfc(v.x); b.y = bfc(v.y); b.z = bfc(v.z); b.w = bfc(v.w);
        *(ushort4*)(xs + row * XS_ROW + col) = b;
    }
    __syncthreads();

    // ---------- Phase 1: QKV for head h; fragments kept in registers ----------
    bf16x8 qf[4], kf[4], vf[2][2];

    #pragma unroll
    for (int mat = 0; mat < 3; ++mat) {
        f32x4 acc[2][4];
        #pragma unroll
        for (int ct = 0; ct < 2; ++ct)
            #pragma unroll
            for (int rt = 0; rt < 4; ++rt)
                acc[ct][rt] = z4;

        const u16* bp0 = wqkvT + (size_t)(mat * 256 + h * 32 + l15) * 256;
        const u16* bp1 = bp0 + 16 * 256;
        __builtin_amdgcn_s_setprio(1);
        #pragma unroll
        for (int ks = 0; ks < 8; ++ks) {
            bf16x8 b0 = *(const bf16x8*)(bp0 + ks * 32 + g * 8);
            bf16x8 b1 = *(const bf16x8*)(bp1 + ks * 32 + g * 8);
            #pragma unroll
            for (int rt = 0; rt < 4; ++rt) {
                bf16x8 a = *(const bf16x8*)(xs + (16 * rt + l15) * XS_ROW + ks * 32 + g * 8);
                acc[0][rt] = __builtin_amdgcn_mfma_f32_16x16x32_bf16(a, b0, acc[0][rt], 0, 0, 0);
                acc[1][rt] = __builtin_amdgcn_mfma_f32_16x16x32_bf16(a, b1, acc[1][rt], 0, 0, 0);
            }
        }
        __builtin_amdgcn_s_setprio(0);
        const float bias0 = bqkv[mat * 256 + h * 32 + l15];
        const float bias1 = bqkv[mat * 256 + h * 32 + 16 + l15];

        asm volatile("s_waitcnt lgkmcnt(0)" ::: "memory");   // WAR: prior buf reads done
        if (mat < 2) {
            // C-layout (lane=d col, row=4g+r) -> A-frag layout, 2 row-tiles per pass
            #pragma unroll
            for (int rp = 0; rp < 2; ++rp) {
                #pragma unroll
                for (int ct = 0; ct < 2; ++ct) {
                    const float bias = ct ? bias1 : bias0;
                    #pragma unroll
                    for (int rtl = 0; rtl < 2; ++rtl)
                        #pragma unroll
                        for (int r = 0; r < 4; ++r)
                            buf[(4 * g + r) * BUF_ROW + rtl * 32 + ct * 16 + l15] =
                                bfc(acc[ct][2 * rp + rtl][r] + bias);
                }
                asm volatile("s_waitcnt lgkmcnt(0)" ::: "memory");
                #pragma unroll
                for (int rtl = 0; rtl < 2; ++rtl) {
                    bf16x8 fr = *(const bf16x8*)(buf + l15 * BUF_ROW + rtl * 32 + g * 8);
                    if (mat == 0) qf[2 * rp + rtl] = fr; else kf[2 * rp + rtl] = fr;
                }
                asm volatile("s_waitcnt lgkmcnt(0)" ::: "memory");   // WAR before next pass
            }
        } else {
            // v transposed: one cd (16 d-cols) per pass; token index packed b64
            #pragma unroll
            for (int cd = 0; cd < 2; ++cd) {
                const float bias = cd ? bias1 : bias0;
                #pragma unroll
                for (int rt = 0; rt < 4; ++rt) {
                    ushort4 pk;
                    pk.x = bfc(acc[cd][rt][0] + bias);
                    pk.y = bfc(acc[cd][rt][1] + bias);
                    pk.z = bfc(acc[cd][rt][2] + bias);
                    pk.w = bfc(acc[cd][rt][3] + bias);
                    *(ushort4*)(buf + l15 * BUF_ROW + 16 * rt + 4 * g) = pk;
                }
                asm volatile("s_waitcnt lgkmcnt(0)" ::: "memory");
                #pragma unroll
                for (int ks = 0; ks < 2; ++ks)
                    vf[ks][cd] = *(const bf16x8*)(buf + l15 * BUF_ROW + ks * 32 + g * 8);
                asm volatile("s_waitcnt lgkmcnt(0)" ::: "memory");   // WAR before next pass
            }
        }
    }
    __syncthreads();   // all xs reads done -> ao may alias xs

    // ---------- Phase 2: attention (wave-private; P via buf) ----------
    const float* b2 = relb + h * 127;
    const float scale = 0.17677669529663687f;   // 1/sqrt(32)
    u16* ao = xs;

    #pragma unroll
    for (int rt = 0; rt < 4; ++rt) {
        f32x4 s[4];
        #pragma unroll
        for (int ct = 0; ct < 4; ++ct)
            s[ct] = __builtin_amdgcn_mfma_f32_16x16x32_bf16(qf[rt], kf[ct], z4, 0, 0, 0);

        asm volatile("s_waitcnt lgkmcnt(0)" ::: "memory");   // WAR: prev rt's pf reads done
        float psum[4] = {0.f, 0.f, 0.f, 0.f};
        #pragma unroll
        for (int ct = 0; ct < 4; ++ct) {
            const int ktok = 16 * ct + l15;
            #pragma unroll
            for (int r = 0; r < 4; ++r) {
                const int qtok = 16 * rt + 4 * g + r;
                float sv = s[ct][r] * scale + b2[ktok - qtok + 63];
                float ee = __expf(sv);
                psum[r] += ee;
                buf[(4 * g + r) * BUF_ROW + ct * 16 + l15] = bfc(ee);
            }
        }
        float inv[4];
        #pragma unroll
        for (int r = 0; r < 4; ++r) {
            float sum = psum[r];
            #pragma unroll
            for (int m = 1; m <= 8; m <<= 1)
                sum += __shfl_xor(sum, m, 64);
            inv[r] = 1.0f / sum;
        }
        asm volatile("s_waitcnt lgkmcnt(0)" ::: "memory");
        bf16x8 pf0 = *(const bf16x8*)(buf + l15 * BUF_ROW + g * 8);
        bf16x8 pf1 = *(const bf16x8*)(buf + l15 * BUF_ROW + 32 + g * 8);
        #pragma unroll
        for (int cd = 0; cd < 2; ++cd) {
            f32x4 o = __builtin_amdgcn_mfma_f32_16x16x32_bf16(pf0, vf[0][cd], z4, 0, 0, 0);
            o = __builtin_amdgcn_mfma_f32_16x16x32_bf16(pf1, vf[1][cd], o, 0, 0, 0);
            #pragma unroll
            for (int r = 0; r < 4; ++r)
                ao[(16 * rt + 4 * g + r) * XS_ROW + h * 32 + cd * 16 + l15] = bfc(o[r] * inv[r]);
        }
        asm volatile("s_waitcnt lgkmcnt(0)" ::: "memory");   // WAR before next rt
    }
    __syncthreads();   // ao complete (cross-wave input to proj)

    // ---------- Phase 3: output projection (wave h -> cols h*32..+31) ----------
    f32x4 pacc[2][4];
    #pragma unroll
    for (int ct = 0; ct < 2; ++ct)
        #pragma unroll
        for (int rt = 0; rt < 4; ++rt)
            pacc[ct][rt] = z4;

    const u16* pp0 = wprojT + (size_t)(h * 32 + l15) * 256;
    const u16* pp1 = pp0 + 16 * 256;
    __builtin_amdgcn_s_setprio(1);
    #pragma unroll
    for (int ks = 0; ks < 8; ++ks) {
        bf16x8 b0 = *(const bf16x8*)(pp0 + ks * 32 + g * 8);
        bf16x8 b1 = *(const bf16x8*)(pp1 + ks * 32 + g * 8);
        #pragma unroll
        for (int rt = 0; rt < 4; ++rt) {
            bf16x8 a = *(const bf16x8*)(ao + (16 * rt + l15) * XS_ROW + ks * 32 + g * 8);
            pacc[0][rt] = __builtin_amdgcn_mfma_f32_16x16x32_bf16(a, b0, pacc[0][rt], 0, 0, 0);
            pacc[1][rt] = __builtin_amdgcn_mfma_f32_16x16x32_bf16(a, b1, pacc[1][rt], 0, 0, 0);
        }
    }
    __builtin_amdgcn_s_setprio(0);

    float* outw = out + (size_t)w * (W * D);
    #pragma unroll
    for (int ct = 0; ct < 2; ++ct) {
        const int n = h * 32 + ct * 16 + l15;
        const float bp = bproj[n];
        #pragma unroll
        for (int rt = 0; rt < 4; ++rt)
            #pragma unroll
            for (int r = 0; r < 4; ++r)
                outw[(16 * rt + 4 * g + r) * D + n] = pacc[ct][rt][r] + bp;
    }
}

// Transpose + bf16-convert the weight matrices into workspace (L2-resident).
__global__ void prep_weights(const float* __restrict__ wqkv, const float* __restrict__ wproj,
                             u16* __restrict__ wqkvT, u16* __restrict__ wprojT)
{
    int i = blockIdx.x * 256 + threadIdx.x;
    if (i < 768 * 256) {
        int n = i >> 8, kk = i & 255;
        wqkvT[i] = bfc(wqkv[kk * 768 + n]);
    } else {
        int j = i - 768 * 256;
        int n = j >> 8, kk = j & 255;
        wprojT[j] = bfc(wproj[kk * 256 + n]);
    }
}

extern "C" void kernel_launch(void* const* d_in, const int* in_sizes, int n_in,
                              void* d_out, int out_size, void* d_ws, size_t ws_size,
                              hipStream_t stream)
{
    const float* x     = (const float*)d_in[0];
    const float* wqkv  = (const float*)d_in[1];
    const float* bqkv  = (const float*)d_in[2];
    const float* wproj = (const float*)d_in[3];
    const float* bproj = (const float*)d_in[4];
    const float* relb  = (const float*)d_in[5];

    u16* wqkvT  = (u16*)d_ws;                 // 768*256 u16
    u16* wprojT = wqkvT + 768 * 256;          // 256*256 u16

    prep_weights<<<1024, 256, 0, stream>>>(wqkv, wproj, wqkvT, wprojT);

    const int nwin = in_sizes[0] / (W * D);   // 4096
    win_attn12<<<nwin, 512, 0, stream>>>(x, bqkv, bproj, relb, wqkvT, wprojT, (float*)d_out);
}

// Round 17
// 333.792 us; speedup vs baseline: 1.6429x; 1.1031x over previous
//
#include <hip/hip_runtime.h>
#include <hip/hip_bf16.h>

#define W 64
#define D 256
#define NH 8

typedef unsigned short u16;
typedef __attribute__((ext_vector_type(8))) short bf16x8;
typedef __attribute__((ext_vector_type(4))) float f32x4;

// Native RNE f32->bf16 cast: compiler emits v_cvt_pk_bf16_f32 for pairs.
__device__ __forceinline__ u16 bfc(float f) {
    __hip_bfloat16 h = __float2bfloat16(f);
    return *reinterpret_cast<u16*>(&h);
}

// ---------------- LDS layout (bytes) ----------------
// xs  : [64][264] u16   x bf16 staging; dead after QKV; aliased by attn_out  33792
// buf : per-wave [16][72] u16 transposer (q/k 2-pass, v 2-pass, P)            2304 x 8
// total 52224. Occupancy is register-capped at 2 blocks/CU; the full
// lgkmcnt(0) drains are the proven no-spill regalloc anchor (R9/R13/R14/R16:
// removing, replacing, or perturbing them with setprio spills). This round:
// R10 verbatim + native bf16 cast ONLY (single-variable VALU experiment).
#define XS_ROW 264
#define BUF_ROW 72
#define OFF_BUF 33792

__global__ __launch_bounds__(512, 4) void win_attn13(
    const float* __restrict__ x, const float* __restrict__ bqkv,
    const float* __restrict__ bproj, const float* __restrict__ relb,
    const u16* __restrict__ wqkvT, const u16* __restrict__ wprojT,
    float* __restrict__ out)
{
    __shared__ __align__(16) char smem[52224];

    const int tid  = threadIdx.x;
    const int lane = tid & 63;
    const int h    = tid >> 6;      // wave index == head
    const int l15  = lane & 15;
    const int g    = lane >> 4;
    const int w    = blockIdx.x;

    u16* xs  = (u16*)smem;
    u16* buf = (u16*)(smem + OFF_BUF) + h * 16 * BUF_ROW;

    const f32x4 z4 = {0.f, 0.f, 0.f, 0.f};

    // ---------- Phase 0: stage x window -> LDS bf16 ----------
    const float* xw = x + (size_t)w * (W * D);
    #pragma unroll
    for (int i = 0; i < 8; ++i) {
        int e = i * 2048 + tid * 4;
        int row = e >> 8, col = e & 255;
        float4 v = *(const float4*)(xw + e);
        ushort4 b;
        b.x = bfc(v.x); b.y = bfc(v.y); b.z = bfc(v.z); b.w = bfc(v.w);
        *(ushort4*)(xs + row * XS_ROW + col) = b;
    }
    __syncthreads();

    // ---------- Phase 1: QKV for head h; fragments kept in registers ----------
    bf16x8 qf[4], kf[4], vf[2][2];

    #pragma unroll
    for (int mat = 0; mat < 3; ++mat) {
        f32x4 acc[2][4];
        #pragma unroll
        for (int ct = 0; ct < 2; ++ct)
            #pragma unroll
            for (int rt = 0; rt < 4; ++rt)
                acc[ct][rt] = z4;

        const u16* bp0 = wqkvT + (size_t)(mat * 256 + h * 32 + l15) * 256;
        const u16* bp1 = bp0 + 16 * 256;
        #pragma unroll
        for (int ks = 0; ks < 8; ++ks) {
            bf16x8 b0 = *(const bf16x8*)(bp0 + ks * 32 + g * 8);
            bf16x8 b1 = *(const bf16x8*)(bp1 + ks * 32 + g * 8);
            #pragma unroll
            for (int rt = 0; rt < 4; ++rt) {
                bf16x8 a = *(const bf16x8*)(xs + (16 * rt + l15) * XS_ROW + ks * 32 + g * 8);
                acc[0][rt] = __builtin_amdgcn_mfma_f32_16x16x32_bf16(a, b0, acc[0][rt], 0, 0, 0);
                acc[1][rt] = __builtin_amdgcn_mfma_f32_16x16x32_bf16(a, b1, acc[1][rt], 0, 0, 0);
            }
        }
        const float bias0 = bqkv[mat * 256 + h * 32 + l15];
        const float bias1 = bqkv[mat * 256 + h * 32 + 16 + l15];

        asm volatile("s_waitcnt lgkmcnt(0)" ::: "memory");   // WAR: prior buf reads done
        if (mat < 2) {
            // C-layout (lane=d col, row=4g+r) -> A-frag layout, 2 row-tiles per pass
            #pragma unroll
            for (int rp = 0; rp < 2; ++rp) {
                #pragma unroll
                for (int ct = 0; ct < 2; ++ct) {
                    const float bias = ct ? bias1 : bias0;
                    #pragma unroll
                    for (int rtl = 0; rtl < 2; ++rtl)
                        #pragma unroll
                        for (int r = 0; r < 4; ++r)
                            buf[(4 * g + r) * BUF_ROW + rtl * 32 + ct * 16 + l15] =
                                bfc(acc[ct][2 * rp + rtl][r] + bias);
                }
                asm volatile("s_waitcnt lgkmcnt(0)" ::: "memory");
                #pragma unroll
                for (int rtl = 0; rtl < 2; ++rtl) {
                    bf16x8 fr = *(const bf16x8*)(buf + l15 * BUF_ROW + rtl * 32 + g * 8);
                    if (mat == 0) qf[2 * rp + rtl] = fr; else kf[2 * rp + rtl] = fr;
                }
                asm volatile("s_waitcnt lgkmcnt(0)" ::: "memory");   // WAR before next pass
            }
        } else {
            // v transposed: one cd (16 d-cols) per pass; token index packed b64
            #pragma unroll
            for (int cd = 0; cd < 2; ++cd) {
                const float bias = cd ? bias1 : bias0;
                #pragma unroll
                for (int rt = 0; rt < 4; ++rt) {
                    ushort4 pk;
                    pk.x = bfc(acc[cd][rt][0] + bias);
                    pk.y = bfc(acc[cd][rt][1] + bias);
                    pk.z = bfc(acc[cd][rt][2] + bias);
                    pk.w = bfc(acc[cd][rt][3] + bias);
                    *(ushort4*)(buf + l15 * BUF_ROW + 16 * rt + 4 * g) = pk;
                }
                asm volatile("s_waitcnt lgkmcnt(0)" ::: "memory");
                #pragma unroll
                for (int ks = 0; ks < 2; ++ks)
                    vf[ks][cd] = *(const bf16x8*)(buf + l15 * BUF_ROW + ks * 32 + g * 8);
                asm volatile("s_waitcnt lgkmcnt(0)" ::: "memory");   // WAR before next pass
            }
        }
    }
    __syncthreads();   // all xs reads done -> ao may alias xs

    // ---------- Phase 2: attention (wave-private; P via buf) ----------
    const float* b2 = relb + h * 127;
    const float scale = 0.17677669529663687f;   // 1/sqrt(32)
    u16* ao = xs;

    #pragma unroll
    for (int rt = 0; rt < 4; ++rt) {
        f32x4 s[4];
        #pragma unroll
        for (int ct = 0; ct < 4; ++ct)
            s[ct] = __builtin_amdgcn_mfma_f32_16x16x32_bf16(qf[rt], kf[ct], z4, 0, 0, 0);

        asm volatile("s_waitcnt lgkmcnt(0)" ::: "memory");   // WAR: prev rt's pf reads done
        float psum[4] = {0.f, 0.f, 0.f, 0.f};
        #pragma unroll
        for (int ct = 0; ct < 4; ++ct) {
            const int ktok = 16 * ct + l15;
            #pragma unroll
            for (int r = 0; r < 4; ++r) {
                const int qtok = 16 * rt + 4 * g + r;
                float sv = s[ct][r] * scale + b2[ktok - qtok + 63];
                float ee = __expf(sv);
                psum[r] += ee;
                buf[(4 * g + r) * BUF_ROW + ct * 16 + l15] = bfc(ee);
            }
        }
        float inv[4];
        #pragma unroll
        for (int r = 0; r < 4; ++r) {
            float sum = psum[r];
            #pragma unroll
            for (int m = 1; m <= 8; m <<= 1)
                sum += __shfl_xor(sum, m, 64);
            inv[r] = 1.0f / sum;
        }
        asm volatile("s_waitcnt lgkmcnt(0)" ::: "memory");
        bf16x8 pf0 = *(const bf16x8*)(buf + l15 * BUF_ROW + g * 8);
        bf16x8 pf1 = *(const bf16x8*)(buf + l15 * BUF_ROW + 32 + g * 8);
        #pragma unroll
        for (int cd = 0; cd < 2; ++cd) {
            f32x4 o = __builtin_amdgcn_mfma_f32_16x16x32_bf16(pf0, vf[0][cd], z4, 0, 0, 0);
            o = __builtin_amdgcn_mfma_f32_16x16x32_bf16(pf1, vf[1][cd], o, 0, 0, 0);
            #pragma unroll
            for (int r = 0; r < 4; ++r)
                ao[(16 * rt + 4 * g + r) * XS_ROW + h * 32 + cd * 16 + l15] = bfc(o[r] * inv[r]);
        }
        asm volatile("s_waitcnt lgkmcnt(0)" ::: "memory");   // WAR before next rt
    }
    __syncthreads();   // ao complete (cross-wave input to proj)

    // ---------- Phase 3: output projection (wave h -> cols h*32..+31) ----------
    f32x4 pacc[2][4];
    #pragma unroll
    for (int ct = 0; ct < 2; ++ct)
        #pragma unroll
        for (int rt = 0; rt < 4; ++rt)
            pacc[ct][rt] = z4;

    const u16* pp0 = wprojT + (size_t)(h * 32 + l15) * 256;
    const u16* pp1 = pp0 + 16 * 256;
    #pragma unroll
    for (int ks = 0; ks < 8; ++ks) {
        bf16x8 b0 = *(const bf16x8*)(pp0 + ks * 32 + g * 8);
        bf16x8 b1 = *(const bf16x8*)(pp1 + ks * 32 + g * 8);
        #pragma unroll
        for (int rt = 0; rt < 4; ++rt) {
            bf16x8 a = *(const bf16x8*)(ao + (16 * rt + l15) * XS_ROW + ks * 32 + g * 8);
            pacc[0][rt] = __builtin_amdgcn_mfma_f32_16x16x32_bf16(a, b0, pacc[0][rt], 0, 0, 0);
            pacc[1][rt] = __builtin_amdgcn_mfma_f32_16x16x32_bf16(a, b1, pacc[1][rt], 0, 0, 0);
        }
    }
    float* outw = out + (size_t)w * (W * D);
    #pragma unroll
    for (int ct = 0; ct < 2; ++ct) {
        const int n = h * 32 + ct * 16 + l15;
        const float bp = bproj[n];
        #pragma unroll
        for (int rt = 0; rt < 4; ++rt)
            #pragma unroll
            for (int r = 0; r < 4; ++r)
                outw[(16 * rt + 4 * g + r) * D + n] = pacc[ct][rt][r] + bp;
    }
}

// Transpose + bf16-convert the weight matrices into workspace (L2-resident).
__global__ void prep_weights(const float* __restrict__ wqkv, const float* __restrict__ wproj,
                             u16* __restrict__ wqkvT, u16* __restrict__ wprojT)
{
    int i = blockIdx.x * 256 + threadIdx.x;
    if (i < 768 * 256) {
        int n = i >> 8, kk = i & 255;
        wqkvT[i] = bfc(wqkv[kk * 768 + n]);
    } else {
        int j = i - 768 * 256;
        int n = j >> 8, kk = j & 255;
        wprojT[j] = bfc(wproj[kk * 256 + n]);
    }
}

extern "C" void kernel_launch(void* const* d_in, const int* in_sizes, int n_in,
                              void* d_out, int out_size, void* d_ws, size_t ws_size,
                              hipStream_t stream)
{
    const float* x     = (const float*)d_in[0];
    const float* wqkv  = (const float*)d_in[1];
    const float* bqkv  = (const float*)d_in[2];
    const float* wproj = (const float*)d_in[3];
    const float* bproj = (const float*)d_in[4];
    const float* relb  = (const float*)d_in[5];

    u16* wqkvT  = (u16*)d_ws;                 // 768*256 u16
    u16* wprojT = wqkvT + 768 * 256;          // 256*256 u16

    prep_weights<<<1024, 256, 0, stream>>>(wqkv, wproj, wqkvT, wprojT);

    const int nwin = in_sizes[0] / (W * D);   // 4096
    win_attn13<<<nwin, 512, 0, stream>>>(x, bqkv, bproj, relb, wqkvT, wprojT, (float*)d_out);
}

// Round 18
// 331.847 us; speedup vs baseline: 1.6525x; 1.0059x over previous
//
#include <hip/hip_runtime.h>
#include <hip/hip_bf16.h>

#define W 64
#define D 256
#define NH 8

typedef unsigned short u16;
typedef __attribute__((ext_vector_type(8))) short bf16x8;
typedef __attribute__((ext_vector_type(4))) float f32x4;

// Native RNE f32->bf16 cast: compiler emits v_cvt_pk_bf16_f32 for pairs.
__device__ __forceinline__ u16 bfc(float f) {
    __hip_bfloat16 h = __float2bfloat16(f);
    return *reinterpret_cast<u16*>(&h);
}

// ---------------- LDS layout (bytes) ----------------
// xs   : [64][264] u16   x bf16 staging; dead after QKV; aliased by attn_out 33792
// buf  : per-wave [16][72] u16 transposer (q/k 2-pass, v 2-pass, P)           2304 x 8
// bias : [8][128] f32 rel-pos bias table                                      4096
// total 56320 -> 2 blocks/CU. R17 anchor + two register-neutral softmax-path
// cuts: bias via LDS (not 64 global loads), scale folded into q fragments.
// Full lgkmcnt(0) drains kept verbatim (the proven no-spill regalloc anchor).
#define XS_ROW 264
#define BUF_ROW 72
#define OFF_BUF 33792
#define OFF_BIAS 52224

__global__ __launch_bounds__(512, 4) void win_attn14(
    const float* __restrict__ x, const float* __restrict__ bqkv,
    const float* __restrict__ bproj, const float* __restrict__ relb,
    const u16* __restrict__ wqkvT, const u16* __restrict__ wprojT,
    float* __restrict__ out)
{
    __shared__ __align__(16) char smem[56320];

    const int tid  = threadIdx.x;
    const int lane = tid & 63;
    const int h    = tid >> 6;      // wave index == head
    const int l15  = lane & 15;
    const int g    = lane >> 4;
    const int w    = blockIdx.x;

    u16*   xs      = (u16*)smem;
    u16*   buf     = (u16*)(smem + OFF_BUF) + h * 16 * BUF_ROW;
    float* bias_ld = (float*)(smem + OFF_BIAS);

    const f32x4 z4 = {0.f, 0.f, 0.f, 0.f};
    const float scale = 0.17677669529663687f;   // 1/sqrt(32)

    // ---------- Phase 0: bias table + stage x window -> LDS bf16 ----------
    for (int i = tid; i < NH * 127; i += 512)
        bias_ld[(i / 127) * 128 + (i % 127)] = relb[i];

    const float* xw = x + (size_t)w * (W * D);
    #pragma unroll
    for (int i = 0; i < 8; ++i) {
        int e = i * 2048 + tid * 4;
        int row = e >> 8, col = e & 255;
        float4 v = *(const float4*)(xw + e);
        ushort4 b;
        b.x = bfc(v.x); b.y = bfc(v.y); b.z = bfc(v.z); b.w = bfc(v.w);
        *(ushort4*)(xs + row * XS_ROW + col) = b;
    }
    __syncthreads();

    // ---------- Phase 1: QKV for head h; fragments kept in registers ----------
    bf16x8 qf[4], kf[4], vf[2][2];

    #pragma unroll
    for (int mat = 0; mat < 3; ++mat) {
        f32x4 acc[2][4];
        #pragma unroll
        for (int ct = 0; ct < 2; ++ct)
            #pragma unroll
            for (int rt = 0; rt < 4; ++rt)
                acc[ct][rt] = z4;

        const u16* bp0 = wqkvT + (size_t)(mat * 256 + h * 32 + l15) * 256;
        const u16* bp1 = bp0 + 16 * 256;
        #pragma unroll
        for (int ks = 0; ks < 8; ++ks) {
            bf16x8 b0 = *(const bf16x8*)(bp0 + ks * 32 + g * 8);
            bf16x8 b1 = *(const bf16x8*)(bp1 + ks * 32 + g * 8);
            #pragma unroll
            for (int rt = 0; rt < 4; ++rt) {
                bf16x8 a = *(const bf16x8*)(xs + (16 * rt + l15) * XS_ROW + ks * 32 + g * 8);
                acc[0][rt] = __builtin_amdgcn_mfma_f32_16x16x32_bf16(a, b0, acc[0][rt], 0, 0, 0);
                acc[1][rt] = __builtin_amdgcn_mfma_f32_16x16x32_bf16(a, b1, acc[1][rt], 0, 0, 0);
            }
        }
        const float bias0 = bqkv[mat * 256 + h * 32 + l15];
        const float bias1 = bqkv[mat * 256 + h * 32 + 16 + l15];

        asm volatile("s_waitcnt lgkmcnt(0)" ::: "memory");   // WAR: prior buf reads done
        if (mat < 2) {
            // q gets scale folded in; k unscaled. 2 row-tiles per pass.
            const float mul = (mat == 0) ? scale : 1.0f;
            #pragma unroll
            for (int rp = 0; rp < 2; ++rp) {
                #pragma unroll
                for (int ct = 0; ct < 2; ++ct) {
                    const float bias = ct ? bias1 : bias0;
                    #pragma unroll
                    for (int rtl = 0; rtl < 2; ++rtl)
                        #pragma unroll
                        for (int r = 0; r < 4; ++r)
                            buf[(4 * g + r) * BUF_ROW + rtl * 32 + ct * 16 + l15] =
                                bfc((acc[ct][2 * rp + rtl][r] + bias) * mul);
                }
                asm volatile("s_waitcnt lgkmcnt(0)" ::: "memory");
                #pragma unroll
                for (int rtl = 0; rtl < 2; ++rtl) {
                    bf16x8 fr = *(const bf16x8*)(buf + l15 * BUF_ROW + rtl * 32 + g * 8);
                    if (mat == 0) qf[2 * rp + rtl] = fr; else kf[2 * rp + rtl] = fr;
                }
                asm volatile("s_waitcnt lgkmcnt(0)" ::: "memory");   // WAR before next pass
            }
        } else {
            // v transposed: one cd (16 d-cols) per pass; token index packed b64
            #pragma unroll
            for (int cd = 0; cd < 2; ++cd) {
                const float bias = cd ? bias1 : bias0;
                #pragma unroll
                for (int rt = 0; rt < 4; ++rt) {
                    ushort4 pk;
                    pk.x = bfc(acc[cd][rt][0] + bias);
                    pk.y = bfc(acc[cd][rt][1] + bias);
                    pk.z = bfc(acc[cd][rt][2] + bias);
                    pk.w = bfc(acc[cd][rt][3] + bias);
                    *(ushort4*)(buf + l15 * BUF_ROW + 16 * rt + 4 * g) = pk;
                }
                asm volatile("s_waitcnt lgkmcnt(0)" ::: "memory");
                #pragma unroll
                for (int ks = 0; ks < 2; ++ks)
                    vf[ks][cd] = *(const bf16x8*)(buf + l15 * BUF_ROW + ks * 32 + g * 8);
                asm volatile("s_waitcnt lgkmcnt(0)" ::: "memory");   // WAR before next pass
            }
        }
    }
    __syncthreads();   // all xs reads done -> ao may alias xs

    // ---------- Phase 2: attention (wave-private; P via buf; bias via LDS) ----------
    const float* b2 = bias_ld + h * 128;
    u16* ao = xs;

    #pragma unroll
    for (int rt = 0; rt < 4; ++rt) {
        f32x4 s[4];
        #pragma unroll
        for (int ct = 0; ct < 4; ++ct)
            s[ct] = __builtin_amdgcn_mfma_f32_16x16x32_bf16(qf[rt], kf[ct], z4, 0, 0, 0);

        asm volatile("s_waitcnt lgkmcnt(0)" ::: "memory");   // WAR: prev rt's pf reads done
        float psum[4] = {0.f, 0.f, 0.f, 0.f};
        #pragma unroll
        for (int ct = 0; ct < 4; ++ct) {
            const int ktok = 16 * ct + l15;
            #pragma unroll
            for (int r = 0; r < 4; ++r) {
                const int qtok = 16 * rt + 4 * g + r;
                float sv = s[ct][r] + b2[ktok - qtok + 63];   // scale already in q
                float ee = __expf(sv);
                psum[r] += ee;
                buf[(4 * g + r) * BUF_ROW + ct * 16 + l15] = bfc(ee);
            }
        }
        float inv[4];
        #pragma unroll
        for (int r = 0; r < 4; ++r) {
            float sum = psum[r];
            #pragma unroll
            for (int m = 1; m <= 8; m <<= 1)
                sum += __shfl_xor(sum, m, 64);
            inv[r] = 1.0f / sum;
        }
        asm volatile("s_waitcnt lgkmcnt(0)" ::: "memory");
        bf16x8 pf0 = *(const bf16x8*)(buf + l15 * BUF_ROW + g * 8);
        bf16x8 pf1 = *(const bf16x8*)(buf + l15 * BUF_ROW + 32 + g * 8);
        #pragma unroll
        for (int cd = 0; cd < 2; ++cd) {
            f32x4 o = __builtin_amdgcn_mfma_f32_16x16x32_bf16(pf0, vf[0][cd], z4, 0, 0, 0);
            o = __builtin_amdgcn_mfma_f32_16x16x32_bf16(pf1, vf[1][cd], o, 0, 0, 0);
            #pragma unroll
            for (int r = 0; r < 4; ++r)
                ao[(16 * rt + 4 * g + r) * XS_ROW + h * 32 + cd * 16 + l15] = bfc(o[r] * inv[r]);
        }
        asm volatile("s_waitcnt lgkmcnt(0)" ::: "memory");   // WAR before next rt
    }
    __syncthreads();   // ao complete (cross-wave input to proj)

    // ---------- Phase 3: output projection (wave h -> cols h*32..+31) ----------
    f32x4 pacc[2][4];
    #pragma unroll
    for (int ct = 0; ct < 2; ++ct)
        #pragma unroll
        for (int rt = 0; rt < 4; ++rt)
            pacc[ct][rt] = z4;

    const u16* pp0 = wprojT + (size_t)(h * 32 + l15) * 256;
    const u16* pp1 = pp0 + 16 * 256;
    #pragma unroll
    for (int ks = 0; ks < 8; ++ks) {
        bf16x8 b0 = *(const bf16x8*)(pp0 + ks * 32 + g * 8);
        bf16x8 b1 = *(const bf16x8*)(pp1 + ks * 32 + g * 8);
        #pragma unroll
        for (int rt = 0; rt < 4; ++rt) {
            bf16x8 a = *(const bf16x8*)(ao + (16 * rt + l15) * XS_ROW + ks * 32 + g * 8);
            pacc[0][rt] = __builtin_amdgcn_mfma_f32_16x16x32_bf16(a, b0, pacc[0][rt], 0, 0, 0);
            pacc[1][rt] = __builtin_amdgcn_mfma_f32_16x16x32_bf16(a, b1, pacc[1][rt], 0, 0, 0);
        }
    }
    float* outw = out + (size_t)w * (W * D);
    #pragma unroll
    for (int ct = 0; ct < 2; ++ct) {
        const int n = h * 32 + ct * 16 + l15;
        const float bp = bproj[n];
        #pragma unroll
        for (int rt = 0; rt < 4; ++rt)
            #pragma unroll
            for (int r = 0; r < 4; ++r)
                outw[(16 * rt + 4 * g + r) * D + n] = pacc[ct][rt][r] + bp;
    }
}

// Transpose + bf16-convert the weight matrices into workspace (L2-resident).
__global__ void prep_weights(const float* __restrict__ wqkv, const float* __restrict__ wproj,
                             u16* __restrict__ wqkvT, u16* __restrict__ wprojT)
{
    int i = blockIdx.x * 256 + threadIdx.x;
    if (i < 768 * 256) {
        int n = i >> 8, kk = i & 255;
        wqkvT[i] = bfc(wqkv[kk * 768 + n]);
    } else {
        int j = i - 768 * 256;
        int n = j >> 8, kk = j & 255;
        wprojT[j] = bfc(wproj[kk * 256 + n]);
    }
}

extern "C" void kernel_launch(void* const* d_in, const int* in_sizes, int n_in,
                              void* d_out, int out_size, void* d_ws, size_t ws_size,
                              hipStream_t stream)
{
    const float* x     = (const float*)d_in[0];
    const float* wqkv  = (const float*)d_in[1];
    const float* bqkv  = (const float*)d_in[2];
    const float* wproj = (const float*)d_in[3];
    const float* bproj = (const float*)d_in[4];
    const float* relb  = (const float*)d_in[5];

    u16* wqkvT  = (u16*)d_ws;                 // 768*256 u16
    u16* wprojT = wqkvT + 768 * 256;          // 256*256 u16

    prep_weights<<<1024, 256, 0, stream>>>(wqkv, wproj, wqkvT, wprojT);

    const int nwin = in_sizes[0] / (W * D);   // 4096
    win_attn14<<<nwin, 512, 0, stream>>>(x, bqkv, bproj, relb, wqkvT, wprojT, (float*)d_out);
}

// Round 19
// 319.315 us; speedup vs baseline: 1.7174x; 1.0392x over previous
//
#include <hip/hip_runtime.h>
#include <hip/hip_bf16.h>

#define W 64
#define D 256
#define NH 8

typedef unsigned short u16;
typedef unsigned int u32;
typedef __attribute__((ext_vector_type(8))) short bf16x8;
typedef __attribute__((ext_vector_type(4))) float f32x4;

// Native RNE f32->bf16 cast: compiler emits v_cvt_pk_bf16_f32 for pairs.
__device__ __forceinline__ u16 bfc(float f) {
    __hip_bfloat16 h = __float2bfloat16(f);
    return *reinterpret_cast<u16*>(&h);
}

// Sum over the 16-lane DPP row (VALU pipe, not DS): ror8, ror4, xor2, xor1.
__device__ __forceinline__ float row16_sum(float x) {
    int t;
    t = __builtin_amdgcn_update_dpp(0, __builtin_bit_cast(int, x), 0x128, 0xf, 0xf, true); // row_ror:8
    x += __builtin_bit_cast(float, t);
    t = __builtin_amdgcn_update_dpp(0, __builtin_bit_cast(int, x), 0x124, 0xf, 0xf, true); // row_ror:4
    x += __builtin_bit_cast(float, t);
    t = __builtin_amdgcn_update_dpp(0, __builtin_bit_cast(int, x), 78, 0xf, 0xf, true);    // quad_perm [2,3,0,1]
    x += __builtin_bit_cast(float, t);
    t = __builtin_amdgcn_update_dpp(0, __builtin_bit_cast(int, x), 177, 0xf, 0xf, true);   // quad_perm [1,0,3,2]
    x += __builtin_bit_cast(float, t);
    return x;
}

// ---------------- LDS layout (bytes) ----------------
// xs   : [64][264] u16   x bf16 staging; dead after QKV; aliased by attn_out 33792
// buf  : per-wave [16][72] u16 transposer (q/k 2-pass, v 2-pass, P)           2304 x 8
// bias : [8][128] f32 rel-pos bias table                                      4096
// total 56320 -> 2 blocks/CU. R18 skeleton; DS-op diet via consistent
// contraction-index permutations (R12-verified algebra):
//  q/k: channel 16b+a stored at column 2a+b (sigma on BOTH Q,K -> S exact)
//  P/v: token  16b+a stored at column 4a+b (sigma on BOTH P,V -> PV exact)
// -> packed u32/b64 transposer writes (no same-dword scalar conflicts),
//    shfl->DPP reduction (off the DS pipe). Drains kept verbatim.
#define XS_ROW 264
#define BUF_ROW 72
#define OFF_BUF 33792
#define OFF_BIAS 52224

__global__ __launch_bounds__(512, 4) void win_attn15(
    const float* __restrict__ x, const float* __restrict__ bqkv,
    const float* __restrict__ bproj, const float* __restrict__ relb,
    const u16* __restrict__ wqkvT, const u16* __restrict__ wprojT,
    float* __restrict__ out)
{
    __shared__ __align__(16) char smem[56320];

    const int tid  = threadIdx.x;
    const int lane = tid & 63;
    const int h    = tid >> 6;      // wave index == head
    const int l15  = lane & 15;
    const int g    = lane >> 4;
    const int w    = blockIdx.x;

    u16*   xs      = (u16*)smem;
    u16*   buf     = (u16*)(smem + OFF_BUF) + h * 16 * BUF_ROW;
    float* bias_ld = (float*)(smem + OFF_BIAS);

    const f32x4 z4 = {0.f, 0.f, 0.f, 0.f};
    const float scale = 0.17677669529663687f;   // 1/sqrt(32)

    // ---------- Phase 0: bias table + stage x window -> LDS bf16 ----------
    for (int i = tid; i < NH * 127; i += 512)
        bias_ld[(i / 127) * 128 + (i % 127)] = relb[i];

    const float* xw = x + (size_t)w * (W * D);
    #pragma unroll
    for (int i = 0; i < 8; ++i) {
        int e = i * 2048 + tid * 4;
        int row = e >> 8, col = e & 255;
        float4 v = *(const float4*)(xw + e);
        ushort4 b;
        b.x = bfc(v.x); b.y = bfc(v.y); b.z = bfc(v.z); b.w = bfc(v.w);
        *(ushort4*)(xs + row * XS_ROW + col) = b;
    }
    __syncthreads();

    // ---------- Phase 1: QKV for head h; fragments kept in registers ----------
    bf16x8 qf[4], kf[4], vf[2][2];

    #pragma unroll
    for (int mat = 0; mat < 3; ++mat) {
        f32x4 acc[2][4];
        #pragma unroll
        for (int ct = 0; ct < 2; ++ct)
            #pragma unroll
            for (int rt = 0; rt < 4; ++rt)
                acc[ct][rt] = z4;

        const u16* bp0 = wqkvT + (size_t)(mat * 256 + h * 32 + l15) * 256;
        const u16* bp1 = bp0 + 16 * 256;
        #pragma unroll
        for (int ks = 0; ks < 8; ++ks) {
            bf16x8 b0 = *(const bf16x8*)(bp0 + ks * 32 + g * 8);
            bf16x8 b1 = *(const bf16x8*)(bp1 + ks * 32 + g * 8);
            #pragma unroll
            for (int rt = 0; rt < 4; ++rt) {
                bf16x8 a = *(const bf16x8*)(xs + (16 * rt + l15) * XS_ROW + ks * 32 + g * 8);
                acc[0][rt] = __builtin_amdgcn_mfma_f32_16x16x32_bf16(a, b0, acc[0][rt], 0, 0, 0);
                acc[1][rt] = __builtin_amdgcn_mfma_f32_16x16x32_bf16(a, b1, acc[1][rt], 0, 0, 0);
            }
        }
        const float bias0 = bqkv[mat * 256 + h * 32 + l15];
        const float bias1 = bqkv[mat * 256 + h * 32 + 16 + l15];

        asm volatile("s_waitcnt lgkmcnt(0)" ::: "memory");   // WAR: prior buf reads done
        if (mat < 2) {
            // sigma32: channel 16*ct + l15 -> column 2*l15 + ct. Packed u32 writes.
            // q gets scale folded in; k unscaled. 2 row-tiles per pass.
            const float mul = (mat == 0) ? scale : 1.0f;
            #pragma unroll
            for (int rp = 0; rp < 2; ++rp) {
                #pragma unroll
                for (int rtl = 0; rtl < 2; ++rtl)
                    #pragma unroll
                    for (int r = 0; r < 4; ++r) {
                        u32 lo = bfc((acc[0][2 * rp + rtl][r] + bias0) * mul);
                        u32 hi = bfc((acc[1][2 * rp + rtl][r] + bias1) * mul);
                        *(u32*)(buf + (4 * g + r) * BUF_ROW + rtl * 32 + 2 * l15) =
                            lo | (hi << 16);
                    }
                asm volatile("s_waitcnt lgkmcnt(0)" ::: "memory");
                #pragma unroll
                for (int rtl = 0; rtl < 2; ++rtl) {
                    bf16x8 fr = *(const bf16x8*)(buf + l15 * BUF_ROW + rtl * 32 + g * 8);
                    if (mat == 0) qf[2 * rp + rtl] = fr; else kf[2 * rp + rtl] = fr;
                }
                asm volatile("s_waitcnt lgkmcnt(0)" ::: "memory");   // WAR before next pass
            }
        } else {
            // sigma64 on tokens: token t -> column 4*(t&15) + (t>>4).
            // t = 16*rt + 4*g + r2 -> column 16*g + 4*r2 + rt: pack across rt.
            #pragma unroll
            for (int cd = 0; cd < 2; ++cd) {
                const float bias = cd ? bias1 : bias0;
                #pragma unroll
                for (int r2 = 0; r2 < 4; ++r2) {
                    ushort4 pk;
                    pk.x = bfc(acc[cd][0][r2] + bias);
                    pk.y = bfc(acc[cd][1][r2] + bias);
                    pk.z = bfc(acc[cd][2][r2] + bias);
                    pk.w = bfc(acc[cd][3][r2] + bias);
                    *(ushort4*)(buf + l15 * BUF_ROW + 16 * g + 4 * r2) = pk;
                }
                asm volatile("s_waitcnt lgkmcnt(0)" ::: "memory");
                #pragma unroll
                for (int ks = 0; ks < 2; ++ks)
                    vf[ks][cd] = *(const bf16x8*)(buf + l15 * BUF_ROW + ks * 32 + g * 8);
                asm volatile("s_waitcnt lgkmcnt(0)" ::: "memory");   // WAR before next pass
            }
        }
    }
    __syncthreads();   // all xs reads done -> ao may alias xs

    // ---------- Phase 2: attention (wave-private; P via buf; bias via LDS) ----------
    const float* b2 = bias_ld + h * 128;
    u16* ao = xs;

    #pragma unroll
    for (int rt = 0; rt < 4; ++rt) {
        f32x4 s[4];
        #pragma unroll
        for (int ct = 0; ct < 4; ++ct)
            s[ct] = __builtin_amdgcn_mfma_f32_16x16x32_bf16(qf[rt], kf[ct], z4, 0, 0, 0);

        asm volatile("s_waitcnt lgkmcnt(0)" ::: "memory");   // WAR: prev rt's pf reads done
        float psum[4];
        #pragma unroll
        for (int r = 0; r < 4; ++r) {
            const int qtok = 16 * rt + 4 * g + r;
            // P[q][k]: token k = 16*ct + l15 stored at column 4*l15 + ct (sigma64)
            float e0 = __expf(s[0][r] + b2[     l15 - qtok + 63]);
            float e1 = __expf(s[1][r] + b2[16 + l15 - qtok + 63]);
            float e2 = __expf(s[2][r] + b2[32 + l15 - qtok + 63]);
            float e3 = __expf(s[3][r] + b2[48 + l15 - qtok + 63]);
            psum[r] = (e0 + e1) + (e2 + e3);
            ushort4 pk;
            pk.x = bfc(e0); pk.y = bfc(e1); pk.z = bfc(e2); pk.w = bfc(e3);
            *(ushort4*)(buf + (4 * g + r) * BUF_ROW + 4 * l15) = pk;
        }
        float inv[4];
        #pragma unroll
        for (int r = 0; r < 4; ++r)
            inv[r] = 1.0f / row16_sum(psum[r]);

        asm volatile("s_waitcnt lgkmcnt(0)" ::: "memory");
        bf16x8 pf0 = *(const bf16x8*)(buf + l15 * BUF_ROW + g * 8);
        bf16x8 pf1 = *(const bf16x8*)(buf + l15 * BUF_ROW + 32 + g * 8);
        #pragma unroll
        for (int cd = 0; cd < 2; ++cd) {
            f32x4 o = __builtin_amdgcn_mfma_f32_16x16x32_bf16(pf0, vf[0][cd], z4, 0, 0, 0);
            o = __builtin_amdgcn_mfma_f32_16x16x32_bf16(pf1, vf[1][cd], o, 0, 0, 0);
            #pragma unroll
            for (int r = 0; r < 4; ++r)
                ao[(16 * rt + 4 * g + r) * XS_ROW + h * 32 + cd * 16 + l15] = bfc(o[r] * inv[r]);
        }
        asm volatile("s_waitcnt lgkmcnt(0)" ::: "memory");   // WAR before next rt
    }
    __syncthreads();   // ao complete (cross-wave input to proj)

    // ---------- Phase 3: output projection (wave h -> cols h*32..+31) ----------
    f32x4 pacc[2][4];
    #pragma unroll
    for (int ct = 0; ct < 2; ++ct)
        #pragma unroll
        for (int rt = 0; rt < 4; ++rt)
            pacc[ct][rt] = z4;

    const u16* pp0 = wprojT + (size_t)(h * 32 + l15) * 256;
    const u16* pp1 = pp0 + 16 * 256;
    #pragma unroll
    for (int ks = 0; ks < 8; ++ks) {
        bf16x8 b0 = *(const bf16x8*)(pp0 + ks * 32 + g * 8);
        bf16x8 b1 = *(const bf16x8*)(pp1 + ks * 32 + g * 8);
        #pragma unroll
        for (int rt = 0; rt < 4; ++rt) {
            bf16x8 a = *(const bf16x8*)(ao + (16 * rt + l15) * XS_ROW + ks * 32 + g * 8);
            pacc[0][rt] = __builtin_amdgcn_mfma_f32_16x16x32_bf16(a, b0, pacc[0][rt], 0, 0, 0);
            pacc[1][rt] = __builtin_amdgcn_mfma_f32_16x16x32_bf16(a, b1, pacc[1][rt], 0, 0, 0);
        }
    }
    float* outw = out + (size_t)w * (W * D);
    #pragma unroll
    for (int ct = 0; ct < 2; ++ct) {
        const int n = h * 32 + ct * 16 + l15;
        const float bp = bproj[n];
        #pragma unroll
        for (int rt = 0; rt < 4; ++rt)
            #pragma unroll
            for (int r = 0; r < 4; ++r)
                outw[(16 * rt + 4 * g + r) * D + n] = pacc[ct][rt][r] + bp;
    }
}

// Transpose + bf16-convert the weight matrices into workspace (L2-resident).
__global__ void prep_weights(const float* __restrict__ wqkv, const float* __restrict__ wproj,
                             u16* __restrict__ wqkvT, u16* __restrict__ wprojT)
{
    int i = blockIdx.x * 256 + threadIdx.x;
    if (i < 768 * 256) {
        int n = i >> 8, kk = i & 255;
        wqkvT[i] = bfc(wqkv[kk * 768 + n]);
    } else {
        int j = i - 768 * 256;
        int n = j >> 8, kk = j & 255;
        wprojT[j] = bfc(wproj[kk * 256 + n]);
    }
}

extern "C" void kernel_launch(void* const* d_in, const int* in_sizes, int n_in,
                              void* d_out, int out_size, void* d_ws, size_t ws_size,
                              hipStream_t stream)
{
    const float* x     = (const float*)d_in[0];
    const float* wqkv  = (const float*)d_in[1];
    const float* bqkv  = (const float*)d_in[2];
    const float* wproj = (const float*)d_in[3];
    const float* bproj = (const float*)d_in[4];
    const float* relb  = (const float*)d_in[5];

    u16* wqkvT  = (u16*)d_ws;                 // 768*256 u16
    u16* wprojT = wqkvT + 768 * 256;          // 256*256 u16

    prep_weights<<<1024, 256, 0, stream>>>(wqkv, wproj, wqkvT, wprojT);

    const int nwin = in_sizes[0] / (W * D);   // 4096
    win_attn15<<<nwin, 512, 0, stream>>>(x, bqkv, bproj, relb, wqkvT, wprojT, (float*)d_out);
}